// Round 1
// baseline (389.670 us; speedup 1.0000x reference)
//
#include <hip/hip_runtime.h>
#include <math.h>

#define H 512
#define NH 8
#define NG 256
#define SPLIT 4

// ---- workspace layout (float offsets) ----
#define WS_QK   0          // 4096 floats : qk[j][h]  (j<512, h<8)
#define WS_SB   4096       // 8 floats    : k_b . q_h per head
#define WS_SEG  4352       // 257 ints    : segment starts
#define WS_VWT  8192       // 262144      : v_w^T  [j][o]
#define WS_OWT  270336     // 262144      : o_w^T  [k][o]
#define WS_TP   532480     // NG*SPLIT*NH*H = 4194304 : T partials
#define WS_DP   4726784    // NG*SPLIT*NH   = 8192    : denom partials
// total ~18.94 MB of d_ws

// ---------------- setup kernels ----------------

__global__ __launch_bounds__(256) void k_seg(const int* __restrict__ batch, int N,
                                             int* __restrict__ seg) {
  int g = blockIdx.x * 256 + threadIdx.x;
  if (g > NG) return;
  int lo = 0, hi = N;
  while (lo < hi) { int mid = (lo + hi) >> 1; if (batch[mid] < g) lo = mid + 1; else hi = mid; }
  seg[g] = lo;   // first index with batch[i] >= g ; seg[NG] = N
}

__global__ __launch_bounds__(256) void k_qk(const float* __restrict__ k_w,
                                            const float* __restrict__ k_b,
                                            const float* __restrict__ query,
                                            float* __restrict__ qk, float* __restrict__ sb) {
  int gt = blockIdx.x * 256 + threadIdx.x;   // 4096 threads
  int h = gt >> 9, j = gt & 511;
  float a = 0.f;
#pragma unroll 8
  for (int d = 0; d < 64; ++d)
    a = fmaf(k_w[(size_t)(h * 64 + d) * H + j], query[h * 64 + d], a);
  qk[j * 8 + h] = a;
  if (gt < 8) {
    float s = 0.f;
    for (int d = 0; d < 64; ++d) s = fmaf(k_b[gt * 64 + d], query[gt * 64 + d], s);
    sb[gt] = s;
  }
}

__global__ __launch_bounds__(256) void k_transpose(const float* __restrict__ vw,
                                                   const float* __restrict__ ow,
                                                   float* __restrict__ vwt,
                                                   float* __restrict__ owt) {
  __shared__ float tile[32][33];
  const float* in  = (blockIdx.y == 0) ? vw  : ow;
  float*       out = (blockIdx.y == 0) ? vwt : owt;
  int b = blockIdx.x;                 // 256 tiles of 32x32
  int bx = b & 15, by = b >> 4;
  int tx = threadIdx.x & 31, ty = threadIdx.x >> 5;   // ty 0..7
#pragma unroll
  for (int k = 0; k < 4; ++k)
    tile[ty + 8 * k][tx] = in[(size_t)(by * 32 + ty + 8 * k) * H + bx * 32 + tx];
  __syncthreads();
#pragma unroll
  for (int k = 0; k < 4; ++k)
    out[(size_t)(bx * 32 + ty + 8 * k) * H + by * 32 + tx] = tile[tx][ty + 8 * k];
}

// ---------------- main single-pass kernel ----------------

__device__ __forceinline__ float dpp_add(float v, int t) { return v + __int_as_float(t); }

__device__ __forceinline__ float wave_allreduce(float v) {
  // sum within each 16-lane row via DPP row_ror (VALU pipe, keeps LDS pipe free)
  v = dpp_add(v, __builtin_amdgcn_update_dpp(0, __float_as_int(v), 0x128, 0xf, 0xf, false));
  v = dpp_add(v, __builtin_amdgcn_update_dpp(0, __float_as_int(v), 0x124, 0xf, 0xf, false));
  v = dpp_add(v, __builtin_amdgcn_update_dpp(0, __float_as_int(v), 0x122, 0xf, 0xf, false));
  v = dpp_add(v, __builtin_amdgcn_update_dpp(0, __float_as_int(v), 0x121, 0xf, 0xf, false));
  // cross-row (2 LDS-pipe ops instead of 48)
  v += __shfl_xor(v, 16, 64);
  v += __shfl_xor(v, 32, 64);
  return v;
}

__global__ __launch_bounds__(256, 2) void k_main(
    const float* __restrict__ x, const float* __restrict__ qk, const float* __restrict__ sb,
    const int* __restrict__ seg, float* __restrict__ T_part, float* __restrict__ den_part) {
  const int g = blockIdx.x >> 2, p = blockIdx.x & (SPLIT - 1);
  const int s0 = seg[g], e0 = seg[g + 1], len = e0 - s0;
  const int na = s0 + (len * p) / SPLIT;
  const int nb = s0 + (len * (p + 1)) / SPLIT;
  const int lane = threadIdx.x & 63, wid = threadIdx.x >> 6;

  // per-lane column ownership: cols {4l..4l+3} and {256+4l..256+4l+3}
  float qk_r[8][8];   // [ci][h]
#pragma unroll
  for (int ci = 0; ci < 8; ++ci) {
    int j = (ci < 4) ? (4 * lane + ci) : (256 + 4 * lane + ci - 4);
    const float4* row = (const float4*)(qk + j * 8);
    float4 q0 = row[0], q1 = row[1];
    qk_r[ci][0] = q0.x; qk_r[ci][1] = q0.y; qk_r[ci][2] = q0.z; qk_r[ci][3] = q0.w;
    qk_r[ci][4] = q1.x; qk_r[ci][5] = q1.y; qk_r[ci][6] = q1.z; qk_r[ci][7] = q1.w;
  }
  float sbr[8];
#pragma unroll
  for (int h = 0; h < 8; ++h) sbr[h] = sb[h];

  float T_r[8][8];    // [h][ci]
  float den[8];
#pragma unroll
  for (int h = 0; h < 8; ++h) {
    den[h] = 0.f;
#pragma unroll
    for (int ci = 0; ci < 8; ++ci) T_r[h][ci] = 0.f;
  }

  const float4* x4 = (const float4*)x;
  int n = na + wid;                    // waves stride by 4 nodes
  float4 xa, xb;
  if (n < nb) { size_t base = (size_t)n * 128 + lane; xa = x4[base]; xb = x4[base + 64]; }
  while (n < nb) {
    int n2 = n + 4;
    float4 ya, yb;
    if (n2 < nb) { size_t b2 = (size_t)n2 * 128 + lane; ya = x4[b2]; yb = x4[b2 + 64]; }

    float xv[8] = {xa.x, xa.y, xa.z, xa.w, xb.x, xb.y, xb.z, xb.w};
    float pp[8] = {0.f, 0.f, 0.f, 0.f, 0.f, 0.f, 0.f, 0.f};
#pragma unroll
    for (int ci = 0; ci < 8; ++ci)
#pragma unroll
      for (int h = 0; h < 8; ++h) pp[h] = fmaf(xv[ci], qk_r[ci][h], pp[h]);

    float w[8];
#pragma unroll
    for (int h = 0; h < 8; ++h) {
      float s = wave_allreduce(pp[h]);
      w[h] = __expf((s + sbr[h]) * 0.125f);   // softmax shift-invariant: no max needed
      den[h] += w[h];
    }
#pragma unroll
    for (int h = 0; h < 8; ++h)
#pragma unroll
      for (int ci = 0; ci < 8; ++ci) T_r[h][ci] = fmaf(w[h], xv[ci], T_r[h][ci]);

    xa = ya; xb = yb; n = n2;
  }

  // combine the 4 waves' register tiles in LDS, then one coalesced global write
  __shared__ float T_lds[8][512];
  __shared__ float den_lds[4][8];
  for (int wv = 0; wv < 4; ++wv) {
    if (wid == wv) {
#pragma unroll
      for (int h = 0; h < 8; ++h) {
        float4 v0 = make_float4(T_r[h][0], T_r[h][1], T_r[h][2], T_r[h][3]);
        float4 v1 = make_float4(T_r[h][4], T_r[h][5], T_r[h][6], T_r[h][7]);
        float4* d0 = (float4*)&T_lds[h][4 * lane];
        float4* d1 = (float4*)&T_lds[h][256 + 4 * lane];
        if (wv == 0) { *d0 = v0; *d1 = v1; }
        else {
          float4 o0 = *d0, o1 = *d1;
          o0.x += v0.x; o0.y += v0.y; o0.z += v0.z; o0.w += v0.w;
          o1.x += v1.x; o1.y += v1.y; o1.z += v1.z; o1.w += v1.w;
          *d0 = o0; *d1 = o1;
        }
      }
      if (lane == 0) {
#pragma unroll
        for (int h = 0; h < 8; ++h) den_lds[wv][h] = den[h];
      }
    }
    __syncthreads();
  }
  const int gp = blockIdx.x;
  float4* Tp4 = (float4*)(T_part + (size_t)gp * (NH * H));
  const float4* Tl4 = (const float4*)T_lds;
  for (int k = threadIdx.x; k < NH * H / 4; k += 256) Tp4[k] = Tl4[k];
  if (threadIdx.x < 8) {
    float d = den_lds[0][threadIdx.x] + den_lds[1][threadIdx.x] +
              den_lds[2][threadIdx.x] + den_lds[3][threadIdx.x];
    den_part[gp * 8 + threadIdx.x] = d;
  }
}

// ---------------- per-graph epilogue ----------------

__global__ __launch_bounds__(512, 1) void k_epi(
    const float* __restrict__ T_part, const float* __restrict__ den_part,
    const float* __restrict__ vwt, const float* __restrict__ vb,
    const float* __restrict__ owt, const float* __restrict__ ob,
    const float* __restrict__ lng, const float* __restrict__ lnb,
    float* __restrict__ out) {
  const int g = blockIdx.x;
  const int t = threadIdx.x;
  __shared__ float Tl[NH * H];
  __shared__ float att[H];
  __shared__ float den_s[8], dinv_s[8];
  __shared__ float red1[8], red2[8];

  // phase 1: combine SPLIT partials
  {
    const float4* tp = (const float4*)(T_part + (size_t)g * SPLIT * (NH * H));
    float4* tl4 = (float4*)Tl;
    for (int k = t; k < NH * H / 4; k += 512) {
      float4 acc = tp[k];
#pragma unroll
      for (int p = 1; p < SPLIT; ++p) {
        float4 v = tp[p * (NH * H / 4) + k];
        acc.x += v.x; acc.y += v.y; acc.z += v.z; acc.w += v.w;
      }
      tl4[k] = acc;
    }
    if (t < 8) {
      float d = 0.f;
#pragma unroll
      for (int p = 0; p < SPLIT; ++p) d += den_part[(g * SPLIT + p) * 8 + t];
      den_s[t] = d;
      dinv_s[t] = (d > 0.f) ? 1.f / d : 1.f;
    }
  }
  __syncthreads();

  // phase 2: attended[o] = (v_w_h . T_h + den*v_b) / den
  {
    const int h = t >> 6;
    const float* Th = Tl + h * H;
    float acc = 0.f;
#pragma unroll 8
    for (int j = 0; j < H; ++j) acc = fmaf(Th[j], vwt[(size_t)j * H + t], acc);
    att[t] = (acc + den_s[h] * vb[t]) * dinv_s[h];
  }
  __syncthreads();

  // phase 3: o-projection
  float o = ob[t];
#pragma unroll 8
  for (int k = 0; k < H; ++k) o = fmaf(att[k], owt[(size_t)k * H + t], o);

  // phase 4: layernorm over the 512 outputs
  float r1 = o, r2 = o * o;
#pragma unroll
  for (int m = 1; m < 64; m <<= 1) { r1 += __shfl_xor(r1, m, 64); r2 += __shfl_xor(r2, m, 64); }
  if ((t & 63) == 0) { red1[t >> 6] = r1; red2[t >> 6] = r2; }
  __syncthreads();
  float S1 = 0.f, S2 = 0.f;
#pragma unroll
  for (int w = 0; w < 8; ++w) { S1 += red1[w]; S2 += red2[w]; }
  float mu = S1 * (1.f / 512.f);
  float var = S2 * (1.f / 512.f) - mu * mu;
  float rstd = rsqrtf(var + 1e-5f);
  out[(size_t)g * H + t] = (o - mu) * rstd * lng[t] + lnb[t];
}

// ---------------- launch ----------------

extern "C" void kernel_launch(void* const* d_in, const int* in_sizes, int n_in,
                              void* d_out, int out_size, void* d_ws, size_t ws_size,
                              hipStream_t stream) {
  const float* x     = (const float*)d_in[0];
  const int*   batch = (const int*)d_in[1];
  const float* query = (const float*)d_in[2];
  const float* k_w   = (const float*)d_in[3];
  const float* k_b   = (const float*)d_in[4];
  const float* v_w   = (const float*)d_in[5];
  const float* v_b   = (const float*)d_in[6];
  const float* o_w   = (const float*)d_in[7];
  const float* o_b   = (const float*)d_in[8];
  const float* ln_g  = (const float*)d_in[9];
  const float* ln_b  = (const float*)d_in[10];
  const int N = in_sizes[0] / H;

  float* ws  = (float*)d_ws;
  float* qk  = ws + WS_QK;
  float* sb  = ws + WS_SB;
  int*   seg = (int*)(ws + WS_SEG);
  float* vwt = ws + WS_VWT;
  float* owt = ws + WS_OWT;
  float* Tp  = ws + WS_TP;
  float* dp  = ws + WS_DP;

  hipLaunchKernelGGL(k_seg, dim3(2), dim3(256), 0, stream, batch, N, seg);
  hipLaunchKernelGGL(k_qk, dim3(16), dim3(256), 0, stream, k_w, k_b, query, qk, sb);
  hipLaunchKernelGGL(k_transpose, dim3(256, 2), dim3(256), 0, stream, v_w, o_w, vwt, owt);
  hipLaunchKernelGGL(k_main, dim3(NG * SPLIT), dim3(256), 0, stream, x, qk, sb, seg, Tp, dp);
  hipLaunchKernelGGL(k_epi, dim3(NG), dim3(512), 0, stream, Tp, dp, vwt, v_b, owt, o_b,
                     ln_g, ln_b, (float*)d_out);
}

// Round 2
// 373.164 us; speedup vs baseline: 1.0442x; 1.0442x over previous
//
#include <hip/hip_runtime.h>
#include <math.h>

#define H 512
#define NH 8
#define NG 256
#define SPLIT 4

// ---- workspace layout (float offsets) ----
#define WS_QK   0          // 4096 floats : qk[j][h] pre-scaled by 1/8
#define WS_SB   4096       // 8 floats    : (k_b . q_h)/8
#define WS_SEG  4352       // 257 ints    : segment starts
#define WS_VWT  8192       // 262144      : v_w^T  [j][o]
#define WS_OWT  270336     // 262144      : o_w^T  [k][o]
#define WS_TP   532480     // NG*SPLIT*NH*H = 4194304 : T partials
#define WS_DP   4726784    // NG*SPLIT*NH   = 8192    : denom partials

// ---------------- fused setup kernel ----------------
// blocks 0-1: segment starts; blocks 2-17: qk fold; blocks 18-529: weight transposes

__global__ __launch_bounds__(256) void k_setup(
    const int* __restrict__ batch, int N, int* __restrict__ seg,
    const float* __restrict__ k_w, const float* __restrict__ k_b,
    const float* __restrict__ query, float* __restrict__ qk, float* __restrict__ sb,
    const float* __restrict__ vw, const float* __restrict__ ow,
    float* __restrict__ vwt, float* __restrict__ owt) {
  __shared__ float tile[32][33];
  const int b = blockIdx.x;
  if (b < 2) {
    int g = b * 256 + threadIdx.x;
    if (g > NG) return;
    int lo = 0, hi = N;
    while (lo < hi) { int mid = (lo + hi) >> 1; if (batch[mid] < g) lo = mid + 1; else hi = mid; }
    seg[g] = lo;
  } else if (b < 18) {
    int gt = (b - 2) * 256 + threadIdx.x;       // 4096 values
    int h = gt >> 9, j = gt & 511;
    float a = 0.f;
#pragma unroll 8
    for (int d = 0; d < 64; ++d)
      a = fmaf(k_w[(size_t)(h * 64 + d) * H + j], query[h * 64 + d], a);
    qk[j * 8 + h] = a * 0.125f;                  // fold 1/sqrt(hd)
    if (gt < 8) {
      float s = 0.f;
      for (int d = 0; d < 64; ++d) s = fmaf(k_b[gt * 64 + d], query[gt * 64 + d], s);
      sb[gt] = s * 0.125f;
    }
  } else {
    int bb = b - 18;                             // 512 tiles
    const float* in  = (bb < 256) ? vw  : ow;
    float*       out = (bb < 256) ? vwt : owt;
    int tidx = bb & 255;
    int bx = tidx & 15, by = tidx >> 4;
    int tx = threadIdx.x & 31, ty = threadIdx.x >> 5;
#pragma unroll
    for (int k = 0; k < 4; ++k)
      tile[ty + 8 * k][tx] = in[(size_t)(by * 32 + ty + 8 * k) * H + bx * 32 + tx];
    __syncthreads();
#pragma unroll
    for (int k = 0; k < 4; ++k)
      out[(size_t)(bx * 32 + ty + 8 * k) * H + by * 32 + tx] = tile[tx][ty + 8 * k];
  }
}

// ---------------- main single-pass kernel ----------------

// add-with-DPP step: v += dpp_move(v); pure VALU, no LDS pipe
#define DPP_ADD(v, ctrl, rmask)                                                   \
  v += __int_as_float(__builtin_amdgcn_update_dpp(0, __float_as_int(v), ctrl,     \
                                                  rmask, 0xf, true))

__global__ __launch_bounds__(256, 2) void k_main(
    const float* __restrict__ x, const float* __restrict__ qk, const float* __restrict__ sb,
    const int* __restrict__ seg, float* __restrict__ T_part, float* __restrict__ den_part) {
  const int g = blockIdx.x >> 2, p = blockIdx.x & (SPLIT - 1);
  const int s0 = seg[g], e0 = seg[g + 1], len = e0 - s0;
  const int na = s0 + (len * p) / SPLIT;
  const int nb = s0 + (len * (p + 1)) / SPLIT;
  const int lane = threadIdx.x & 63, wid = threadIdx.x >> 6;

  // per-lane column ownership: cols {4l..4l+3} and {256+4l..256+4l+3}
  float qk_r[8][8];   // [ci][h], pre-scaled by 1/8
#pragma unroll
  for (int ci = 0; ci < 8; ++ci) {
    int j = (ci < 4) ? (4 * lane + ci) : (256 + 4 * lane + ci - 4);
    const float4* row = (const float4*)(qk + j * 8);
    float4 q0 = row[0], q1 = row[1];
    qk_r[ci][0] = q0.x; qk_r[ci][1] = q0.y; qk_r[ci][2] = q0.z; qk_r[ci][3] = q0.w;
    qk_r[ci][4] = q1.x; qk_r[ci][5] = q1.y; qk_r[ci][6] = q1.z; qk_r[ci][7] = q1.w;
  }
  float sbr[8];
#pragma unroll
  for (int h = 0; h < 8; ++h) sbr[h] = sb[h];

  float T_r[8][8];    // [h][ci]
  float den[8];
#pragma unroll
  for (int h = 0; h < 8; ++h) {
    den[h] = 0.f;
#pragma unroll
    for (int ci = 0; ci < 8; ++ci) T_r[h][ci] = 0.f;
  }

  const float4* x4 = (const float4*)x;
  int n = na + wid;                    // waves stride by 4 nodes
  float4 b0a, b0b, b1a, b1b;
  if (n < nb)     { size_t a = (size_t)n * 128 + lane;       b0a = x4[a]; b0b = x4[a + 64]; }
  if (n + 4 < nb) { size_t a = (size_t)(n + 4) * 128 + lane; b1a = x4[a]; b1b = x4[a + 64]; }

  for (; n < nb; n += 4) {
    float4 b2a, b2b;
    if (n + 8 < nb) { size_t a = (size_t)(n + 8) * 128 + lane; b2a = x4[a]; b2b = x4[a + 64]; }

    float xv[8] = {b0a.x, b0a.y, b0a.z, b0a.w, b0b.x, b0b.y, b0b.z, b0b.w};
    float pp[8] = {0.f, 0.f, 0.f, 0.f, 0.f, 0.f, 0.f, 0.f};
#pragma unroll
    for (int ci = 0; ci < 8; ++ci)
#pragma unroll
      for (int h = 0; h < 8; ++h) pp[h] = fmaf(xv[ci], qk_r[ci][h], pp[h]);

    // 64-lane sum, all-DPP (8 independent chains interleaved stepwise)
#pragma unroll
    for (int h = 0; h < 8; ++h) DPP_ADD(pp[h], 0x111, 0xf);   // row_shr:1
#pragma unroll
    for (int h = 0; h < 8; ++h) DPP_ADD(pp[h], 0x112, 0xf);   // row_shr:2
#pragma unroll
    for (int h = 0; h < 8; ++h) DPP_ADD(pp[h], 0x114, 0xf);   // row_shr:4
#pragma unroll
    for (int h = 0; h < 8; ++h) DPP_ADD(pp[h], 0x118, 0xf);   // row_shr:8
#pragma unroll
    for (int h = 0; h < 8; ++h) DPP_ADD(pp[h], 0x142, 0xa);   // row_bcast:15
#pragma unroll
    for (int h = 0; h < 8; ++h) DPP_ADD(pp[h], 0x143, 0xc);   // row_bcast:31

    float w[8];
#pragma unroll
    for (int h = 0; h < 8; ++h) {
      float s = __int_as_float(__builtin_amdgcn_readlane(__float_as_int(pp[h]), 63));
      w[h] = __expf(s + sbr[h]);        // softmax shift-invariant: no max needed
      den[h] += w[h];
    }
#pragma unroll
    for (int h = 0; h < 8; ++h)
#pragma unroll
      for (int ci = 0; ci < 8; ++ci) T_r[h][ci] = fmaf(w[h], xv[ci], T_r[h][ci]);

    b0a = b1a; b0b = b1b; b1a = b2a; b1b = b2b;
  }

  // combine the 4 waves' register tiles in LDS, then one coalesced global write
  __shared__ float T_lds[8][512];
  __shared__ float den_lds[4][8];
  for (int wv = 0; wv < 4; ++wv) {
    if (wid == wv) {
#pragma unroll
      for (int h = 0; h < 8; ++h) {
        float4 v0 = make_float4(T_r[h][0], T_r[h][1], T_r[h][2], T_r[h][3]);
        float4 v1 = make_float4(T_r[h][4], T_r[h][5], T_r[h][6], T_r[h][7]);
        float4* d0 = (float4*)&T_lds[h][4 * lane];
        float4* d1 = (float4*)&T_lds[h][256 + 4 * lane];
        if (wv == 0) { *d0 = v0; *d1 = v1; }
        else {
          float4 o0 = *d0, o1 = *d1;
          o0.x += v0.x; o0.y += v0.y; o0.z += v0.z; o0.w += v0.w;
          o1.x += v1.x; o1.y += v1.y; o1.z += v1.z; o1.w += v1.w;
          *d0 = o0; *d1 = o1;
        }
      }
      if (lane == 0) {
#pragma unroll
        for (int h = 0; h < 8; ++h) den_lds[wv][h] = den[h];
      }
    }
    __syncthreads();
  }
  const int gp = blockIdx.x;
  float4* Tp4 = (float4*)(T_part + (size_t)gp * (NH * H));
  const float4* Tl4 = (const float4*)T_lds;
  for (int k = threadIdx.x; k < NH * H / 4; k += 256) Tp4[k] = Tl4[k];
  if (threadIdx.x < 8) {
    float d = den_lds[0][threadIdx.x] + den_lds[1][threadIdx.x] +
              den_lds[2][threadIdx.x] + den_lds[3][threadIdx.x];
    den_part[gp * 8 + threadIdx.x] = d;
  }
}

// ---------------- per-graph epilogue: 2 graphs per block ----------------

__global__ __launch_bounds__(512) void k_epi(
    const float* __restrict__ T_part, const float* __restrict__ den_part,
    const float* __restrict__ vwt, const float* __restrict__ vb,
    const float* __restrict__ owt, const float* __restrict__ ob,
    const float* __restrict__ lng, const float* __restrict__ lnb,
    float* __restrict__ out) {
  const int g0 = blockIdx.x * 2;
  const int t = threadIdx.x;
  __shared__ float Tl[2][NH * H];     // 32 KB
  __shared__ float att[2][H];
  __shared__ float den_s[2][8], dinv_s[2][8];
  __shared__ float red[2][2][8];

  // phase 1: combine SPLIT partials for both graphs
#pragma unroll
  for (int gi = 0; gi < 2; ++gi) {
    const float4* tp = (const float4*)(T_part + (size_t)(g0 + gi) * SPLIT * (NH * H));
    float4* tl4 = (float4*)Tl[gi];
    for (int k = t; k < NH * H / 4; k += 512) {
      float4 acc = tp[k];
#pragma unroll
      for (int p = 1; p < SPLIT; ++p) {
        float4 v = tp[p * (NH * H / 4) + k];
        acc.x += v.x; acc.y += v.y; acc.z += v.z; acc.w += v.w;
      }
      tl4[k] = acc;
    }
  }
  if (t < 16) {
    int gi = t >> 3, h = t & 7;
    float d = 0.f;
#pragma unroll
    for (int p = 0; p < SPLIT; ++p) d += den_part[((g0 + gi) * SPLIT + p) * 8 + h];
    den_s[gi][h] = d;
    dinv_s[gi][h] = (d > 0.f) ? 1.f / d : 1.f;
  }
  __syncthreads();

  // phase 2: attended = (v_w_h . T_h + den*v_b)/den — weight load shared by 2 graphs
  {
    const int h = t >> 6;
    const float* T0 = &Tl[0][h * H];
    const float* T1 = &Tl[1][h * H];
    float a0 = 0.f, a1 = 0.f;
#pragma unroll 8
    for (int j = 0; j < H; ++j) {
      float wv_ = vwt[(size_t)j * H + t];
      a0 = fmaf(T0[j], wv_, a0);
      a1 = fmaf(T1[j], wv_, a1);
    }
    att[0][t] = (a0 + den_s[0][h] * vb[t]) * dinv_s[0][h];
    att[1][t] = (a1 + den_s[1][h] * vb[t]) * dinv_s[1][h];
  }
  __syncthreads();

  // phase 3: o-projection
  float o0 = ob[t], o1 = o0;
#pragma unroll 8
  for (int k = 0; k < H; ++k) {
    float w_ = owt[(size_t)k * H + t];
    o0 = fmaf(att[0][k], w_, o0);
    o1 = fmaf(att[1][k], w_, o1);
  }

  // phase 4: layernorm for both graphs
  float r10 = o0, r20 = o0 * o0, r11 = o1, r21 = o1 * o1;
#pragma unroll
  for (int m = 1; m < 64; m <<= 1) {
    r10 += __shfl_xor(r10, m, 64); r20 += __shfl_xor(r20, m, 64);
    r11 += __shfl_xor(r11, m, 64); r21 += __shfl_xor(r21, m, 64);
  }
  if ((t & 63) == 0) {
    red[0][0][t >> 6] = r10; red[0][1][t >> 6] = r20;
    red[1][0][t >> 6] = r11; red[1][1][t >> 6] = r21;
  }
  __syncthreads();
  float S10 = 0.f, S20 = 0.f, S11 = 0.f, S21 = 0.f;
#pragma unroll
  for (int w = 0; w < 8; ++w) {
    S10 += red[0][0][w]; S20 += red[0][1][w];
    S11 += red[1][0][w]; S21 += red[1][1][w];
  }
  float mu0 = S10 * (1.f / 512.f), mu1 = S11 * (1.f / 512.f);
  float var0 = S20 * (1.f / 512.f) - mu0 * mu0;
  float var1 = S21 * (1.f / 512.f) - mu1 * mu1;
  float rs0 = rsqrtf(var0 + 1e-5f), rs1 = rsqrtf(var1 + 1e-5f);
  float gg = lng[t], bb = lnb[t];
  out[(size_t)g0 * H + t]       = (o0 - mu0) * rs0 * gg + bb;
  out[(size_t)(g0 + 1) * H + t] = (o1 - mu1) * rs1 * gg + bb;
}

// ---------------- launch ----------------

extern "C" void kernel_launch(void* const* d_in, const int* in_sizes, int n_in,
                              void* d_out, int out_size, void* d_ws, size_t ws_size,
                              hipStream_t stream) {
  const float* x     = (const float*)d_in[0];
  const int*   batch = (const int*)d_in[1];
  const float* query = (const float*)d_in[2];
  const float* k_w   = (const float*)d_in[3];
  const float* k_b   = (const float*)d_in[4];
  const float* v_w   = (const float*)d_in[5];
  const float* v_b   = (const float*)d_in[6];
  const float* o_w   = (const float*)d_in[7];
  const float* o_b   = (const float*)d_in[8];
  const float* ln_g  = (const float*)d_in[9];
  const float* ln_b  = (const float*)d_in[10];
  const int N = in_sizes[0] / H;

  float* ws  = (float*)d_ws;
  float* qk  = ws + WS_QK;
  float* sb  = ws + WS_SB;
  int*   seg = (int*)(ws + WS_SEG);
  float* vwt = ws + WS_VWT;
  float* owt = ws + WS_OWT;
  float* Tp  = ws + WS_TP;
  float* dp  = ws + WS_DP;

  hipLaunchKernelGGL(k_setup, dim3(530), dim3(256), 0, stream,
                     batch, N, seg, k_w, k_b, query, qk, sb, v_w, o_w, vwt, owt);
  hipLaunchKernelGGL(k_main, dim3(NG * SPLIT), dim3(256), 0, stream, x, qk, sb, seg, Tp, dp);
  hipLaunchKernelGGL(k_epi, dim3(NG / 2), dim3(512), 0, stream, Tp, dp, vwt, v_b, owt, o_b,
                     ln_g, ln_b, (float*)d_out);
}